// Round 1
// baseline (32717.532 us; speedup 1.0000x reference)
//
#include <hip/hip_runtime.h>
#include <cstdint>
#include <cstddef>

#define BB    128
#define TFRM  80
#define DECL  30
#define EE    512
#define FEATD 4096
#define VV    6000

using frag_ab = __attribute__((ext_vector_type(8))) short;
using frag_cd = __attribute__((ext_vector_type(4))) float;

__device__ __forceinline__ float sigf(float x)  { return 1.0f / (1.0f + __expf(-x)); }
__device__ __forceinline__ float tanhf_(float x){ float e = __expf(2.0f * x); return 1.0f - 2.0f / (e + 1.0f); }
__device__ __forceinline__ unsigned short f2bf_rne(float x) {
    unsigned int u = __float_as_uint(x);
    u += 0x7fffu + ((u >> 16) & 1u);
    return (unsigned short)(u >> 16);
}

// ---------------- init: zero states + out ----------------
__global__ void init_zero(float* h1, float* h2, float* c1, float* c2, float* out) {
    int i = blockIdx.x * blockDim.x + threadIdx.x;   // 65536 threads
    h1[i] = 0.f; h2[i] = 0.f; c1[i] = 0.f; c2[i] = 0.f;
    if (i == 0) out[0] = 0.f;
}

// ---------------- fp32 -> bf16 convert (RNE), vectorized x4 ----------------
__global__ void f2bf(const float* __restrict__ src, unsigned short* __restrict__ dst, int n4) {
    int i = blockIdx.x * blockDim.x + threadIdx.x;
    if (i >= n4) return;
    float4 v = ((const float4*)src)[i];
    ushort4 o;
    o.x = f2bf_rne(v.x); o.y = f2bf_rne(v.y); o.z = f2bf_rne(v.z); o.w = f2bf_rne(v.w);
    ((ushort4*)dst)[i] = o;
}

// ---------------- argmax over vocab (first-index ties, jnp.argmax semantics) ----------------
__global__ void argmax_k(const float* __restrict__ oh, int* __restrict__ labels) {
    int row = blockIdx.x;                       // b*DECL + t
    const float* p = oh + (size_t)row * VV;
    int lane = threadIdx.x;                     // 64 threads = 1 wave
    float best = -1e30f; int bi = 0x7fffffff;
    for (int v = lane; v < VV; v += 64) {
        float x = p[v];
        if (x > best) { best = x; bi = v; }     // strict > keeps first in this lane's stream
    }
    for (int off = 32; off; off >>= 1) {
        float ob = __shfl_down(best, off);
        int   oi = __shfl_down(bi,   off);
        if (ob > best || (ob == best && oi < bi)) { best = ob; bi = oi; }
    }
    if (lane == 0) labels[row] = bi;
}

// ---------------- P_enc = feat @ w_ih1^T  (bf16 MFMA, 64x64 tile) ----------------
// A: feat_bf laid as original feat [(b*80+t)*4096 + k]; output row r = t*128 + b
// Bw: w_ih1_bf [2048, 4096] row-major (NT gemm: B^T input, k-contiguous)
__global__ __launch_bounds__(256) void gemm_penc(const unsigned short* __restrict__ A,
                                                 const unsigned short* __restrict__ Bw,
                                                 float* __restrict__ C) {
    __shared__ unsigned short As[64][32];
    __shared__ unsigned short Bs[64][32];
    int bm = blockIdx.x % 160;                  // 10240/64
    int bn = blockIdx.x / 160;                  // 2048/64 = 32
    int tid = threadIdx.x;
    int wave = tid >> 6, lane = tid & 63;

    int arow  = tid >> 2;                       // 0..63
    int acol8 = (tid & 3) * 8;                  // 0,8,16,24
    int r  = bm * 64 + arow;
    int gt = r >> 7, gb = r & 127;              // r = t*128 + b
    const unsigned short* Arow = A  + (size_t)(gb * TFRM + gt) * FEATD + acol8;
    const unsigned short* Brow = Bw + (size_t)(bn * 64 + arow) * FEATD + acol8;

    frag_cd acc[4] = {};
    int m16 = lane & 15, kg8 = (lane >> 4) * 8;

    for (int k0 = 0; k0 < FEATD; k0 += 32) {
        *(uint4*)&As[arow][acol8] = *(const uint4*)(Arow + k0);
        *(uint4*)&Bs[arow][acol8] = *(const uint4*)(Brow + k0);
        __syncthreads();
        frag_ab bfrag = *(frag_ab*)&Bs[wave * 16 + m16][kg8];
        #pragma unroll
        for (int mt = 0; mt < 4; ++mt) {
            frag_ab afrag = *(frag_ab*)&As[mt * 16 + m16][kg8];
            acc[mt] = __builtin_amdgcn_mfma_f32_16x16x32_bf16(afrag, bfrag, acc[mt], 0, 0, 0);
        }
        __syncthreads();
    }
    // C/D layout: col = lane&15, row = (lane>>4)*4 + reg  [m89-verified]
    int col = bn * 64 + wave * 16 + (lane & 15);
    #pragma unroll
    for (int mt = 0; mt < 4; ++mt) {
        int rbase = bm * 64 + mt * 16 + (lane >> 4) * 4;
        #pragma unroll
        for (int i = 0; i < 4; ++i)
            C[(size_t)(rbase + i) * 2048 + col] = acc[mt][i];
    }
}

// ---------------- LSTM1 step: gates = [P_enc[t]] + h @ w_hh1^T + b; fused cell update ----------------
__global__ __launch_bounds__(128) void lstm1_step(const float* __restrict__ P,  // [B,2048] slice or null
                                                  const float* __restrict__ h_in,
                                                  float* __restrict__ h_out,
                                                  float* __restrict__ c,        // in-place
                                                  const float* __restrict__ w_hh, // [2048,512]
                                                  const float* __restrict__ b_ih,
                                                  const float* __restrict__ b_hh) {
    __shared__ float hs[EE];
    int b = blockIdx.x >> 2;
    int e = ((blockIdx.x & 3) << 7) + threadIdx.x;
    for (int k = threadIdx.x; k < EE; k += 128) hs[k] = h_in[b * EE + k];
    __syncthreads();
    const float4* hv = (const float4*)hs;
    float acc[4];
    #pragma unroll
    for (int g = 0; g < 4; ++g) {
        int row = g * EE + e;
        const float4* w = (const float4*)(w_hh + (size_t)row * EE);
        float a = 0.f;
        #pragma unroll 4
        for (int k = 0; k < EE / 4; ++k) {
            float4 h4 = hv[k], w4 = w[k];
            a += h4.x * w4.x + h4.y * w4.y + h4.z * w4.z + h4.w * w4.w;
        }
        a += b_ih[row] + b_hh[row];
        if (P) a += P[b * 2048 + row];
        acc[g] = a;
    }
    float ci = c[b * EE + e];
    float cn = sigf(acc[1]) * ci + sigf(acc[0]) * tanhf_(acc[2]);
    float hn = sigf(acc[3]) * tanhf_(cn);
    c[b * EE + e] = cn;
    h_out[b * EE + e] = hn;
}

// ---------------- LSTM2 step: gates = [x @ w_ih2[:, :512]^T] + h1 @ w_ih2[:, 512:]^T + h2 @ w_hh2^T + b ----------------
__global__ __launch_bounds__(128) void lstm2_step(const float* __restrict__ x,   // caption + t*EE (stride DECL*EE) or null
                                                  const float* __restrict__ h1,
                                                  const float* __restrict__ h2_in,
                                                  float* __restrict__ h2_out,
                                                  float* __restrict__ c2,
                                                  const float* __restrict__ w_ih2, // [2048,1024]
                                                  const float* __restrict__ w_hh2, // [2048,512]
                                                  const float* __restrict__ b_ih,
                                                  const float* __restrict__ b_hh) {
    __shared__ float h1s[EE], h2s[EE], xs[EE];
    int b = blockIdx.x >> 2;
    int e = ((blockIdx.x & 3) << 7) + threadIdx.x;
    for (int k = threadIdx.x; k < EE; k += 128) {
        h1s[k] = h1[b * EE + k];
        h2s[k] = h2_in[b * EE + k];
        if (x) xs[k] = x[(size_t)b * DECL * EE + k];
    }
    __syncthreads();
    const float4* h1v = (const float4*)h1s;
    const float4* h2v = (const float4*)h2s;
    const float4* xv  = (const float4*)xs;
    float acc[4];
    #pragma unroll
    for (int g = 0; g < 4; ++g) {
        int row = g * EE + e;
        const float4* wh1 = (const float4*)(w_ih2 + (size_t)row * 1024 + 512);
        const float4* wh2 = (const float4*)(w_hh2 + (size_t)row * EE);
        float a = 0.f;
        #pragma unroll 2
        for (int k = 0; k < EE / 4; ++k) {
            float4 v1 = h1v[k], w1 = wh1[k];
            a += v1.x * w1.x + v1.y * w1.y + v1.z * w1.z + v1.w * w1.w;
            float4 v2 = h2v[k], w2 = wh2[k];
            a += v2.x * w2.x + v2.y * w2.y + v2.z * w2.z + v2.w * w2.w;
        }
        if (x) {
            const float4* wx = (const float4*)(w_ih2 + (size_t)row * 1024);
            #pragma unroll 2
            for (int k = 0; k < EE / 4; ++k) {
                float4 v3 = xv[k], w3 = wx[k];
                a += v3.x * w3.x + v3.y * w3.y + v3.z * w3.z + v3.w * w3.w;
            }
        }
        acc[g] = a + b_ih[row] + b_hh[row];
    }
    float ci = c2[b * EE + e];
    float cn = sigf(acc[1]) * ci + sigf(acc[0]) * tanhf_(acc[2]);
    float hn = sigf(acc[3]) * tanhf_(cn);
    c2[b * EE + e] = cn;
    h2_out[b * EE + e] = hn;
}

// ---------------- decoder loss: logits = h2 @ w_out^T + b_out; NLL of log_softmax at label ----------------
__global__ __launch_bounds__(256) void loss_step(const float* __restrict__ h2,
                                                 const float* __restrict__ w_out, // [V,512]
                                                 const float* __restrict__ b_out,
                                                 const int* __restrict__ labels,  // [B*DECL]
                                                 int tcol,
                                                 float* __restrict__ out) {
    __shared__ float hs[EE];
    __shared__ float lg[VV];
    __shared__ float red[256];
    int b = blockIdx.x;
    for (int k = threadIdx.x; k < EE; k += 256) hs[k] = h2[b * EE + k];
    __syncthreads();
    const float4* hv = (const float4*)hs;
    float lmax = -1e30f;
    for (int v = threadIdx.x; v < VV; v += 256) {
        const float4* w = (const float4*)(w_out + (size_t)v * EE);
        float a = b_out[v];
        #pragma unroll 4
        for (int k = 0; k < EE / 4; ++k) {
            float4 h4 = hv[k], w4 = w[k];
            a += h4.x * w4.x + h4.y * w4.y + h4.z * w4.z + h4.w * w4.w;
        }
        lg[v] = a;
        lmax = fmaxf(lmax, a);
    }
    red[threadIdx.x] = lmax; __syncthreads();
    for (int s = 128; s; s >>= 1) {
        if (threadIdx.x < s) red[threadIdx.x] = fmaxf(red[threadIdx.x], red[threadIdx.x + s]);
        __syncthreads();
    }
    lmax = red[0]; __syncthreads();
    float lsum = 0.f;
    for (int v = threadIdx.x; v < VV; v += 256) lsum += __expf(lg[v] - lmax);
    red[threadIdx.x] = lsum; __syncthreads();
    for (int s = 128; s; s >>= 1) {
        if (threadIdx.x < s) red[threadIdx.x] += red[threadIdx.x + s];
        __syncthreads();
    }
    if (threadIdx.x == 0) {
        int lab = labels[b * DECL + tcol];
        float loss = (lmax + __logf(red[0])) - lg[lab];
        atomicAdd(out, loss * (1.0f / BB));
    }
}

extern "C" void kernel_launch(void* const* d_in, const int* in_sizes, int n_in,
                              void* d_out, int out_size, void* d_ws, size_t ws_size,
                              hipStream_t stream) {
    const float* feat    = (const float*)d_in[0];
    const float* caption = (const float*)d_in[1];
    const float* onehot  = (const float*)d_in[2];
    const float* w_ih1   = (const float*)d_in[3];
    const float* w_hh1   = (const float*)d_in[4];
    const float* b_ih1   = (const float*)d_in[5];
    const float* b_hh1   = (const float*)d_in[6];
    const float* w_ih2   = (const float*)d_in[7];
    const float* w_hh2   = (const float*)d_in[8];
    const float* b_ih2   = (const float*)d_in[9];
    const float* b_hh2   = (const float*)d_in[10];
    const float* w_out   = (const float*)d_in[11];
    const float* b_out   = (const float*)d_in[12];
    float* out = (float*)d_out;

    // workspace layout (need ~186.1 MB)
    char* ws = (char*)d_ws;
    size_t off = 0;
    auto alloc = [&](size_t bytes) -> char* {
        char* p = ws + off;
        off = (off + bytes + 255) & ~(size_t)255;
        return p;
    };
    unsigned short* feat_bf = (unsigned short*)alloc((size_t)BB * TFRM * FEATD * 2);
    unsigned short* wih1_bf = (unsigned short*)alloc((size_t)2048 * FEATD * 2);
    float* P_enc = (float*)alloc((size_t)TFRM * BB * 2048 * 4);
    float* H1a = (float*)alloc((size_t)BB * EE * 4);
    float* H1b = (float*)alloc((size_t)BB * EE * 4);
    float* H2a = (float*)alloc((size_t)BB * EE * 4);
    float* H2b = (float*)alloc((size_t)BB * EE * 4);
    float* C1  = (float*)alloc((size_t)BB * EE * 4);
    float* C2  = (float*)alloc((size_t)BB * EE * 4);
    int* labels = (int*)alloc((size_t)BB * DECL * 4);
    if (off > ws_size) return;  // workspace too small: fail loudly (out stays poisoned)

    init_zero<<<256, 256, 0, stream>>>(H1a, H2a, C1, C2, out);
    {
        int n4 = BB * TFRM * FEATD / 4;
        f2bf<<<(n4 + 255) / 256, 256, 0, stream>>>(feat, feat_bf, n4);
        int m4 = 2048 * FEATD / 4;
        f2bf<<<(m4 + 255) / 256, 256, 0, stream>>>(w_ih1, wih1_bf, m4);
    }
    argmax_k<<<BB * DECL, 64, 0, stream>>>(onehot, labels);
    gemm_penc<<<160 * 32, 256, 0, stream>>>(feat_bf, wih1_bf, P_enc);

    float* h1c = H1a; float* h1n = H1b;
    float* h2c = H2a; float* h2n = H2b;
    for (int t = 0; t < TFRM; ++t) {
        lstm1_step<<<512, 128, 0, stream>>>(P_enc + (size_t)t * BB * 2048, h1c, h1n, C1,
                                            w_hh1, b_ih1, b_hh1);
        { float* tmp = h1c; h1c = h1n; h1n = tmp; }
        lstm2_step<<<512, 128, 0, stream>>>(nullptr, h1c, h2c, h2n, C2,
                                            w_ih2, w_hh2, b_ih2, b_hh2);
        { float* tmp = h2c; h2c = h2n; h2n = tmp; }
    }
    for (int t = 0; t < DECL - 1; ++t) {
        lstm1_step<<<512, 128, 0, stream>>>(nullptr, h1c, h1n, C1,
                                            w_hh1, b_ih1, b_hh1);
        { float* tmp = h1c; h1c = h1n; h1n = tmp; }
        lstm2_step<<<512, 128, 0, stream>>>(caption + (size_t)t * EE, h1c, h2c, h2n, C2,
                                            w_ih2, w_hh2, b_ih2, b_hh2);
        { float* tmp = h2c; h2c = h2n; h2n = tmp; }
        loss_step<<<BB, 256, 0, stream>>>(h2c, w_out, b_out, labels, t + 1, out);
    }
}

// Round 2
// 3059.753 us; speedup vs baseline: 10.6929x; 10.6929x over previous
//
#include <hip/hip_runtime.h>
#include <cstdint>
#include <cstddef>

#define BB    128
#define TFRM  80
#define DECL  30
#define EE    512
#define FEATD 4096
#define VV    6000
#define VPAD  6016

using frag_ab = __attribute__((ext_vector_type(8))) short;
using frag_cd = __attribute__((ext_vector_type(4))) float;

static __device__ __forceinline__ float sigf(float x)  { return 1.0f / (1.0f + __expf(-x)); }
static __device__ __forceinline__ float tanhf_(float x){ float e = __expf(2.0f * x); return 1.0f - 2.0f / (e + 1.0f); }
static __device__ __forceinline__ unsigned short f2bf_rne(float x) {
    unsigned int u = __float_as_uint(x);
    u += 0x7fffu + ((u >> 16) & 1u);
    return (unsigned short)(u >> 16);
}

// ---------------- init: zero h ping-pong buffers (bf16), c states, out ----------------
__global__ void init_zero(unsigned int* h1a, unsigned int* h1b, unsigned int* h2a, unsigned int* h2b,
                          float* c1, float* c2, float* out) {
    int i = blockIdx.x * blockDim.x + threadIdx.x;   // 65536 threads
    if (i < 32768) { h1a[i] = 0u; h1b[i] = 0u; h2a[i] = 0u; h2b[i] = 0u; }
    c1[i] = 0.f; c2[i] = 0.f;
    if (i == 0) out[0] = 0.f;
}

// ---------------- fp32 -> bf16 (RNE), x4 ----------------
__global__ void f2bf(const float* __restrict__ src, unsigned short* __restrict__ dst, int n4) {
    int i = blockIdx.x * blockDim.x + threadIdx.x;
    if (i >= n4) return;
    float4 v = ((const float4*)src)[i];
    ushort4 o;
    o.x = f2bf_rne(v.x); o.y = f2bf_rne(v.y); o.z = f2bf_rne(v.z); o.w = f2bf_rne(v.w);
    ((ushort4*)dst)[i] = o;
}

// ---------------- build Wcat2 [2048,1024] bf16: cols 0..511 = w_ih2[:,512:], cols 512.. = w_hh2 ----------------
__global__ void build_wcat2(const float* __restrict__ w_ih2, const float* __restrict__ w_hh2,
                            unsigned short* __restrict__ dst, int n4) {
    int i = blockIdx.x * blockDim.x + threadIdx.x;   // n4 = 2048*1024/4
    if (i >= n4) return;
    int r  = i >> 8;              // /256
    int c  = (i & 255) * 4;
    const float* src = (c < 512) ? (w_ih2 + (size_t)r * 1024 + 512 + c)
                                 : (w_hh2 + (size_t)r * 512 + (c - 512));
    float4 v = *(const float4*)src;
    ushort4 o;
    o.x = f2bf_rne(v.x); o.y = f2bf_rne(v.y); o.z = f2bf_rne(v.z); o.w = f2bf_rne(v.w);
    ((ushort4*)dst)[i] = o;
}

// ---------------- w_out -> bf16 padded to 6016 rows (pad rows zero) ----------------
__global__ void wout_pad(const float* __restrict__ w_out, unsigned short* __restrict__ dst, int n4) {
    int i = blockIdx.x * blockDim.x + threadIdx.x;   // n4 = 6016*512/4
    if (i >= n4) return;
    int r = i >> 7;               // /128
    int c = (i & 127) * 4;
    ushort4 o;
    if (r < VV) {
        float4 v = *(const float4*)(w_out + (size_t)r * EE + c);
        o.x = f2bf_rne(v.x); o.y = f2bf_rne(v.y); o.z = f2bf_rne(v.z); o.w = f2bf_rne(v.w);
    } else {
        o.x = 0; o.y = 0; o.z = 0; o.w = 0;
    }
    ((ushort4*)dst)[i] = o;
}

// ---------------- gather decoder word inputs: rows r = b*29+t from caption[b][t][:] (t<29), bf16 ----------------
__global__ void xdec_gather(const float* __restrict__ cap, unsigned short* __restrict__ dst, int n4) {
    int i = blockIdx.x * blockDim.x + threadIdx.x;   // n4 = 3712*512/4
    if (i >= n4) return;
    int row = i >> 7;             // /128
    int c   = (i & 127) * 4;
    int b = row / 29, t = row - b * 29;
    float4 v = *(const float4*)(cap + (size_t)(b * DECL + t) * EE + c);
    ushort4 o;
    o.x = f2bf_rne(v.x); o.y = f2bf_rne(v.y); o.z = f2bf_rne(v.z); o.w = f2bf_rne(v.w);
    ((ushort4*)dst)[i] = o;
}

// ---------------- bias sums ----------------
__global__ void bias_sum(const float* b_ih1, const float* b_hh1, const float* b_ih2, const float* b_hh2,
                         float* bs1, float* bs2) {
    int i = blockIdx.x * blockDim.x + threadIdx.x;   // 2048
    bs1[i] = b_ih1[i] + b_hh1[i];
    bs2[i] = b_ih2[i] + b_hh2[i];
}

// ---------------- argmax over vocab (first-index ties) ----------------
__global__ void argmax_k(const float* __restrict__ oh, int* __restrict__ labels) {
    int row = blockIdx.x;                       // b*DECL + t
    const float* p = oh + (size_t)row * VV;
    int lane = threadIdx.x;
    float best = -1e30f; int bi = 0x7fffffff;
    for (int v = lane; v < VV; v += 64) {
        float x = p[v];
        if (x > best) { best = x; bi = v; }
    }
    for (int off = 32; off; off >>= 1) {
        float ob = __shfl_down(best, off);
        int   oi = __shfl_down(bi,   off);
        if (ob > best || (ob == best && oi < bi)) { best = ob; bi = oi; }
    }
    if (lane == 0) labels[row] = bi;
}

// ---------------- generic 64x64 bf16 NT GEMM: C[M,N](fp32,ldc) = A[M,K](lda) @ B[N,K](ldb)^T + bias[col] ----------------
__global__ __launch_bounds__(256) void gemm64(const unsigned short* __restrict__ A, int lda,
                                              const unsigned short* __restrict__ B, int ldb,
                                              float* __restrict__ C, int ldc,
                                              int K, int ntiles,
                                              const float* __restrict__ bias, int biasN) {
    __shared__ unsigned short As[64][40];
    __shared__ unsigned short Bs[64][40];
    int bm = blockIdx.x / ntiles;
    int bn = blockIdx.x % ntiles;
    int tid = threadIdx.x;
    int wave = tid >> 6, lane = tid & 63;

    int srow  = tid >> 2;
    int scol8 = (tid & 3) * 8;
    const unsigned short* Ap = A + (size_t)(bm * 64 + srow) * lda + scol8;
    const unsigned short* Bp = B + (size_t)(bn * 64 + srow) * ldb + scol8;

    frag_cd acc[4] = {};
    int m16 = lane & 15, kg8 = (lane >> 4) * 8;

    for (int k0 = 0; k0 < K; k0 += 32) {
        *(uint4*)&As[srow][scol8] = *(const uint4*)(Ap + k0);
        *(uint4*)&Bs[srow][scol8] = *(const uint4*)(Bp + k0);
        __syncthreads();
        frag_ab bfrag = *(frag_ab*)&Bs[wave * 16 + m16][kg8];
        #pragma unroll
        for (int mt = 0; mt < 4; ++mt) {
            frag_ab afrag = *(frag_ab*)&As[mt * 16 + m16][kg8];
            acc[mt] = __builtin_amdgcn_mfma_f32_16x16x32_bf16(afrag, bfrag, acc[mt], 0, 0, 0);
        }
        __syncthreads();
    }
    int col = bn * 64 + wave * 16 + (lane & 15);
    float bv = 0.f;
    if (bias) bv = (col < biasN) ? bias[col] : 0.f;
    #pragma unroll
    for (int mt = 0; mt < 4; ++mt) {
        int rbase = bm * 64 + mt * 16 + (lane >> 4) * 4;
        #pragma unroll
        for (int i = 0; i < 4; ++i)
            C[(size_t)(rbase + i) * ldc + col] = acc[mt][i] + bv;
    }
}

// ---------------- fused LSTM step: gates MFMA + pointwise cell update ----------------
// W: [2048, K] bf16 (gate-major rows g*512+e). B operand rows = batch:
//   global col k<512 from Xa[b][k], k>=512 from Xb[b][k-512]  (each [128,512] bf16)
// P (optional): fp32, addr = P + b*pstride + gaterow. c fp32 in-place. hout bf16 [128,512].
__global__ __launch_bounds__(256) void lstm_step(const unsigned short* __restrict__ W, int K,
                                                 const unsigned short* __restrict__ Xa,
                                                 const unsigned short* __restrict__ Xb,
                                                 const float* __restrict__ P, int pstride,
                                                 const float* __restrict__ bias,
                                                 float* __restrict__ c,
                                                 unsigned short* __restrict__ hout) {
    __shared__ unsigned short Ws[64][136];
    __shared__ unsigned short Xs[16][136];
    __shared__ float gbuf[4][16][17];

    int et = blockIdx.x >> 3;        // 0..31  e-tile
    int nt = blockIdx.x & 7;         // 0..7   batch-tile
    int e0 = et * 16, b0 = nt * 16;
    int tid = threadIdx.x;
    int wave = tid >> 6, lane = tid & 63;   // wave = gate index
    int m16 = lane & 15, kg8 = (lane >> 4) * 8;

    frag_cd acc = {};

    for (int k0 = 0; k0 < K; k0 += 128) {
        // stage W chunk: 64 rows (4 gates x 16 e) x 128 cols
        #pragma unroll
        for (int p = 0; p < 4; ++p) {
            int lr = p * 16 + (tid >> 4);
            int g = lr >> 4, ei = lr & 15;
            int col8 = (tid & 15) * 8;
            *(uint4*)&Ws[lr][col8] =
                *(const uint4*)(W + (size_t)(g * EE + e0 + ei) * K + k0 + col8);
        }
        // stage X chunk: 16 batch rows x 128 cols
        {
            int r = tid >> 4;
            int col8 = (tid & 15) * 8;
            const unsigned short* src = (k0 < 512)
                ? (Xa + (size_t)(b0 + r) * EE + k0 + col8)
                : (Xb + (size_t)(b0 + r) * EE + (k0 - 512) + col8);
            *(uint4*)&Xs[r][col8] = *(const uint4*)src;
        }
        __syncthreads();
        #pragma unroll
        for (int kk = 0; kk < 4; ++kk) {
            frag_ab af = *(frag_ab*)&Ws[wave * 16 + m16][kk * 32 + kg8];
            frag_ab bf = *(frag_ab*)&Xs[m16][kk * 32 + kg8];
            acc = __builtin_amdgcn_mfma_f32_16x16x32_bf16(af, bf, acc, 0, 0, 0);
        }
        __syncthreads();
    }

    // exchange gates through LDS: tile row = e (A rows), col = batch (B rows)
    {
        int er = (lane >> 4) * 4, cb = lane & 15;
        #pragma unroll
        for (int i = 0; i < 4; ++i) gbuf[wave][er + i][cb] = acc[i];
    }
    __syncthreads();

    // pointwise: one output per thread (16e x 16b)
    {
        int e = tid & 15, b = tid >> 4;
        int row = e0 + e;
        int bg  = b0 + b;
        float gi = gbuf[0][e][b] + bias[row];
        float gf = gbuf[1][e][b] + bias[EE + row];
        float gg = gbuf[2][e][b] + bias[2 * EE + row];
        float go = gbuf[3][e][b] + bias[3 * EE + row];
        if (P) {
            const float* pp = P + (size_t)bg * pstride;
            gi += pp[row]; gf += pp[EE + row]; gg += pp[2 * EE + row]; go += pp[3 * EE + row];
        }
        size_t cidx = (size_t)bg * EE + row;
        float cn = sigf(gf) * c[cidx] + sigf(gi) * tanhf_(gg);
        float hn = sigf(go) * tanhf_(cn);
        c[cidx] = cn;
        hout[(size_t)bg * EE + row] = f2bf_rne(hn);
    }
}

// ---------------- loss reduce over precomputed logits [128, 6016] ----------------
__global__ __launch_bounds__(256) void loss_reduce(const float* __restrict__ logits,
                                                   const int* __restrict__ labels,
                                                   int tcol, float* __restrict__ out) {
    __shared__ float red[256];
    int b = blockIdx.x, tid = threadIdx.x;
    const float* lg = logits + (size_t)b * VPAD;
    float mx = -1e30f;
    for (int v = tid; v < VV; v += 256) mx = fmaxf(mx, lg[v]);
    red[tid] = mx; __syncthreads();
    for (int s = 128; s; s >>= 1) {
        if (tid < s) red[tid] = fmaxf(red[tid], red[tid + s]);
        __syncthreads();
    }
    mx = red[0]; __syncthreads();
    float sm = 0.f;
    for (int v = tid; v < VV; v += 256) sm += __expf(lg[v] - mx);
    red[tid] = sm; __syncthreads();
    for (int s = 128; s; s >>= 1) {
        if (tid < s) red[tid] += red[tid + s];
        __syncthreads();
    }
    if (tid == 0) {
        int lab = labels[b * DECL + tcol];
        atomicAdd(out, (mx + __logf(red[0]) - lg[lab]) * (1.0f / BB));
    }
}

extern "C" void kernel_launch(void* const* d_in, const int* in_sizes, int n_in,
                              void* d_out, int out_size, void* d_ws, size_t ws_size,
                              hipStream_t stream) {
    const float* feat    = (const float*)d_in[0];
    const float* caption = (const float*)d_in[1];
    const float* onehot  = (const float*)d_in[2];
    const float* w_ih1   = (const float*)d_in[3];
    const float* w_hh1   = (const float*)d_in[4];
    const float* b_ih1   = (const float*)d_in[5];
    const float* b_hh1   = (const float*)d_in[6];
    const float* w_ih2   = (const float*)d_in[7];
    const float* w_hh2   = (const float*)d_in[8];
    const float* b_ih2   = (const float*)d_in[9];
    const float* b_hh2   = (const float*)d_in[10];
    const float* w_out   = (const float*)d_in[11];
    const float* b_out   = (const float*)d_in[12];
    float* out = (float*)d_out;

    char* ws = (char*)d_ws;
    size_t off = 0;
    auto alloc = [&](size_t bytes) -> char* {
        char* p = ws + off;
        off = (off + bytes + 255) & ~(size_t)255;
        return p;
    };
    unsigned short* feat_bf  = (unsigned short*)alloc((size_t)BB * TFRM * FEATD * 2);  // 83.9 MB
    unsigned short* wih1_bf  = (unsigned short*)alloc((size_t)2048 * FEATD * 2);       // 16.8 MB
    unsigned short* wih2_bf  = (unsigned short*)alloc((size_t)2048 * 1024 * 2);        // 4.2 MB
    unsigned short* whh1_bf  = (unsigned short*)alloc((size_t)2048 * EE * 2);          // 2.1 MB
    unsigned short* wcat2_bf = (unsigned short*)alloc((size_t)2048 * 1024 * 2);        // 4.2 MB
    unsigned short* wout_bf  = (unsigned short*)alloc((size_t)VPAD * EE * 2);          // 6.2 MB
    float* P_enc = (float*)alloc((size_t)BB * TFRM * 2048 * 4);                        // 83.9 MB
    float* P_dec = (float*)alloc((size_t)BB * 29 * 2048 * 4);                          // 30.4 MB
    unsigned short* xdec_bf = (unsigned short*)alloc((size_t)BB * 29 * EE * 2);        // 3.8 MB
    unsigned short* h1a = (unsigned short*)alloc((size_t)BB * EE * 2);
    unsigned short* h1b = (unsigned short*)alloc((size_t)BB * EE * 2);
    unsigned short* h2a = (unsigned short*)alloc((size_t)BB * EE * 2);
    unsigned short* h2b = (unsigned short*)alloc((size_t)BB * EE * 2);
    float* C1 = (float*)alloc((size_t)BB * EE * 4);
    float* C2 = (float*)alloc((size_t)BB * EE * 4);
    float* logits = (float*)alloc((size_t)BB * VPAD * 4);                              // 3.1 MB
    float* bias1 = (float*)alloc(2048 * 4);
    float* bias2 = (float*)alloc(2048 * 4);
    int* labels = (int*)alloc((size_t)BB * DECL * 4);
    if (off > ws_size) return;  // fail loudly (out stays poisoned)

    init_zero<<<256, 256, 0, stream>>>((unsigned int*)h1a, (unsigned int*)h1b,
                                       (unsigned int*)h2a, (unsigned int*)h2b, C1, C2, out);
    f2bf<<<40960, 256, 0, stream>>>(feat, feat_bf, BB * TFRM * FEATD / 4);
    f2bf<<<8192, 256, 0, stream>>>(w_ih1, wih1_bf, 2048 * FEATD / 4);
    f2bf<<<2048, 256, 0, stream>>>(w_ih2, wih2_bf, 2048 * 1024 / 4);
    f2bf<<<1024, 256, 0, stream>>>(w_hh1, whh1_bf, 2048 * EE / 4);
    build_wcat2<<<2048, 256, 0, stream>>>(w_ih2, w_hh2, wcat2_bf, 2048 * 1024 / 4);
    wout_pad<<<3008, 256, 0, stream>>>(w_out, wout_bf, VPAD * EE / 4);
    xdec_gather<<<1856, 256, 0, stream>>>(caption, xdec_bf, BB * 29 * EE / 4);
    bias_sum<<<8, 256, 0, stream>>>(b_ih1, b_hh1, b_ih2, b_hh2, bias1, bias2);
    argmax_k<<<BB * DECL, 64, 0, stream>>>(onehot, labels);

    // P_enc[(b*80+t), 2048] = feat @ w_ih1^T
    gemm64<<<160 * 32, 256, 0, stream>>>(feat_bf, FEATD, wih1_bf, FEATD, P_enc, 2048,
                                         FEATD, 32, nullptr, 0);
    // P_dec[(b*29+t), 2048] = x_word @ w_ih2[:, :512]^T
    gemm64<<<58 * 32, 256, 0, stream>>>(xdec_bf, EE, wih2_bf, 1024, P_dec, 2048,
                                        EE, 32, nullptr, 0);

    unsigned short *h1c = h1a, *h1n = h1b, *h2c = h2a, *h2n = h2b;
    for (int t = 0; t < TFRM; ++t) {
        lstm_step<<<256, 256, 0, stream>>>(whh1_bf, EE, h1c, nullptr,
                                           P_enc + (size_t)t * 2048, TFRM * 2048,
                                           bias1, C1, h1n);
        { unsigned short* tmp = h1c; h1c = h1n; h1n = tmp; }
        lstm_step<<<256, 256, 0, stream>>>(wcat2_bf, 1024, h1c, h2c, nullptr, 0,
                                           bias2, C2, h2n);
        { unsigned short* tmp = h2c; h2c = h2n; h2n = tmp; }
    }
    for (int t = 0; t < DECL - 1; ++t) {
        lstm_step<<<256, 256, 0, stream>>>(whh1_bf, EE, h1c, nullptr, nullptr, 0,
                                           bias1, C1, h1n);
        { unsigned short* tmp = h1c; h1c = h1n; h1n = tmp; }
        lstm_step<<<256, 256, 0, stream>>>(wcat2_bf, 1024, h1c, h2c,
                                           P_dec + (size_t)t * 2048, 29 * 2048,
                                           bias2, C2, h2n);
        { unsigned short* tmp = h2c; h2c = h2n; h2n = tmp; }
        gemm64<<<2 * 94, 256, 0, stream>>>(h2c, EE, wout_bf, EE, logits, VPAD,
                                           EE, 94, b_out, VV);
        loss_reduce<<<BB, 256, 0, stream>>>(logits, labels, t + 1, out);
    }
}